// Round 7
// baseline (7821.993 us; speedup 1.0000x reference)
//
#include <hip/hip_runtime.h>
#include <hip/hip_cooperative_groups.h>

namespace cg = cooperative_groups;

typedef unsigned short ushort_t;
typedef __attribute__((ext_vector_type(8))) short bf16x8;
typedef __attribute__((ext_vector_type(4))) float f32x4;

#define B_    1024
#define H_    1024
#define FEAT_ 75
#define KP_   1120          // packed K: 1024 h + 75 x + 21 zero pad
#define NKT   35            // K-steps of 32
#define OFF_CP 1920000UL    // 1024*25*75
#define OFF_CV 5760000UL    // OFF_CP + 1024*50*75

// LDS map (bytes) for main_kernel
#define LDS_SCR 24576       // after 3x8192 stage buffers; 8 waves x 1088B
#define LDS_FC  33280       // fc h-rows: 4x1024 f32
#define LDS_TOT 49664

__device__ __forceinline__ float bf2f(ushort_t u) {
    unsigned x = ((unsigned)u) << 16;
    float f; __builtin_memcpy(&f, &x, 4); return f;
}
__device__ __forceinline__ ushort_t f2bf(float f) {
    unsigned x; __builtin_memcpy(&x, &f, 4);
    x += 0x7fffu + ((x >> 16) & 1u);          // RNE
    return (ushort_t)(x >> 16);
}
__device__ __forceinline__ float sigm(float x) { return 1.f / (1.f + __expf(-x)); }

__device__ __forceinline__ void gload16(const void* g, void* l) {
    __builtin_amdgcn_global_load_lds(
        (const __attribute__((address_space(1))) void*)g,
        (__attribute__((address_space(3))) void*)l, 16, 0, 0);
}

// ---------------------------------------------------------------------------
// W-fragments into registers: wave owns 16 gate-cols (4 hidden j x 4 gates),
// 35 K-fragments of bf16x8 = 140 VGPRs, held across all timesteps.
// Fragment: lane l -> gate-col c=l&15 (g=c>>2, jj=c&3), k = kt*32+(l>>4)*8.
// ---------------------------------------------------------------------------
__device__ __forceinline__ void load_w(bf16x8 (&bw)[NKT],
                                       const ushort_t* __restrict__ Wt,
                                       int j0w, int l)
{
    const int c16 = l & 15;
    const size_t row = (size_t)((c16 >> 2) << 10) + (c16 & 3) + j0w;
    const ushort_t* p = Wt + row * KP_ + ((l >> 4) << 3);
    #pragma unroll
    for (int kt = 0; kt < NKT; ++kt)
        bw[kt] = *(const bf16x8*)(p + kt * 32);
}

// ---------------------------------------------------------------------------
// One M=128 GEMM pass + fused LSTM cell. B (weights) from registers; A staged
// via global_load_lds, D=3 double... triple-buffered with counted vmcnt.
// Epilogue: per-wave LDS scratch transposes the 16x16 gate tile so each lane
// gets all 4 gates of one (row, j); c kept in caller's register array.
// ---------------------------------------------------------------------------
__device__ __forceinline__ void run_pass(
    char* lds, const ushort_t* __restrict__ Ain, ushort_t* __restrict__ Aout,
    const bf16x8 (&bw)[NKT], float (&cr)[8],
    float bsi, float bsf, float bsg, float bso,
    int R0, int j0w, int tid, int w, int l,
    int write_c, float* __restrict__ cglob)
{
    const int srow = tid >> 2;
    const ushort_t* asrc = Ain + (size_t)(R0 + srow) * KP_
                         + (((tid & 3) ^ (srow & 3)) << 3);   // inv-swizzled src
    char* adst = lds + (w << 10);                              // wave-uniform
    const int abase = ((l & 15) << 6) + ((((l >> 4) ^ (l & 3))) << 4);
    float* sc = (float*)(lds + LDS_SCR) + w * 272;             // 16x17 f32

    f32x4 acc[8];
    #pragma unroll
    for (int m = 0; m < 8; ++m) acc[m] = (f32x4){0.f, 0.f, 0.f, 0.f};

    asm volatile("s_waitcnt vmcnt(0)" ::: "memory");   // pin vm counter base
    gload16(asrc,      adst);
    gload16(asrc + 32, adst + 8192);

    #pragma unroll
    for (int kt = 0; kt < NKT; ++kt) {
        if (kt + 2 < NKT) {
            gload16(asrc + (kt + 2) * 32, adst + ((kt + 2) % 3) * 8192);
            asm volatile("s_waitcnt vmcnt(2)" ::: "memory");
        } else if (kt + 1 < NKT) {
            asm volatile("s_waitcnt vmcnt(1)" ::: "memory");
        } else {
            asm volatile("s_waitcnt vmcnt(0)" ::: "memory");
        }
        __builtin_amdgcn_s_barrier();
        asm volatile("" ::: "memory");
        const char* bp = lds + (kt % 3) * 8192;
        __builtin_amdgcn_s_setprio(1);
        #pragma unroll
        for (int m = 0; m < 8; ++m) {
            const bf16x8 a = *(const bf16x8*)(bp + (m << 10) + abase);
            acc[m] = __builtin_amdgcn_mfma_f32_16x16x32_bf16(a, bw[kt], acc[m], 0, 0, 0);
        }
        __builtin_amdgcn_s_setprio(0);
        asm volatile("" ::: "memory");
        __builtin_amdgcn_s_barrier();
    }

    const int row2 = l >> 2, jj = l & 3;
    const int jcol = j0w + jj;
    #pragma unroll
    for (int m = 0; m < 8; ++m) {
        #pragma unroll
        for (int r = 0; r < 4; ++r)
            sc[((l >> 4) * 4 + r) * 17 + (l & 15)] = acc[m][r];
        const float gi = sc[row2 * 17 + jj];
        const float gf = sc[row2 * 17 + 4 + jj];
        const float gg = sc[row2 * 17 + 8 + jj];
        const float go = sc[row2 * 17 + 12 + jj];
        const float cn = sigm(gf + bsf) * cr[m] + sigm(gi + bsi) * tanhf(gg + bsg);
        cr[m] = cn;
        const int grow = R0 + (m << 4) + row2;
        Aout[(size_t)grow * KP_ + jcol] = f2bf(sigm(go + bso) * tanhf(cn));
        if (write_c) cglob[((size_t)grow << 10) + jcol] = cn;
    }
}

// ---------------------------------------------------------------------------
// fc phase (decoder): block handles 4 batch rows aligned with its XCD's step
// writers. Fuses clip, comp_vel/comp_pose writes, cumsum, x-feedback.
// ---------------------------------------------------------------------------
__device__ __forceinline__ void fc_phase(
    char* lds, ushort_t* __restrict__ Ah,
    const ushort_t* __restrict__ fcWb, const float* __restrict__ fcb,
    float* __restrict__ accp, float* __restrict__ out,
    int d, int tid, int blk)
{
    float* hs = (float*)(lds + LDS_FC);
    const int r0 = (blk & 7) * 128 + (blk >> 3) * 4;
    {
        const int r = tid >> 7, k8 = (tid & 127) << 3;
        const bf16x8 v = *(const bf16x8*)(Ah + (size_t)(r0 + r) * KP_ + k8);
        #pragma unroll
        for (int u = 0; u < 8; ++u) hs[(r << 10) + k8 + u] = bf2f((ushort_t)v[u]);
    }
    __syncthreads();
    const int r = tid >> 7, f = tid & 127;
    if (f < FEAT_) {
        const ushort_t* wr = fcWb + (size_t)f * 1024;
        const float* hr = hs + (r << 10);
        float s0 = fcb[f], s1 = 0.f, s2 = 0.f, s3 = 0.f;
        for (int k = 0; k < 1024; k += 32) {
            const bf16x8 w0 = *(const bf16x8*)(wr + k);
            const bf16x8 w1 = *(const bf16x8*)(wr + k + 8);
            const bf16x8 w2 = *(const bf16x8*)(wr + k + 16);
            const bf16x8 w3 = *(const bf16x8*)(wr + k + 24);
            #pragma unroll
            for (int u = 0; u < 8; ++u) {
                s0 = fmaf(hr[k + u],      bf2f((ushort_t)w0[u]), s0);
                s1 = fmaf(hr[k + 8 + u],  bf2f((ushort_t)w1[u]), s1);
                s2 = fmaf(hr[k + 16 + u], bf2f((ushort_t)w2[u]), s2);
                s3 = fmaf(hr[k + 24 + u], bf2f((ushort_t)w3[u]), s3);
            }
        }
        float s = (s0 + s1) + (s2 + s3);
        s = fminf(fmaxf(s, -1.f), 1.f);
        const int row = r0 + r;
        const float pnew = accp[row * FEAT_ + f] + s;
        accp[row * FEAT_ + f] = pnew;
        out[OFF_CV + ((size_t)row * 49 + d) * FEAT_ + f]     = s;
        out[OFF_CP + ((size_t)row * 50 + d + 1) * FEAT_ + f] = pnew;
        Ah[(size_t)row * KP_ + 1024 + f] = f2bf(s);
    }
    __syncthreads();
}

// ---------------------------------------------------------------------------
struct MainArgs {
    ushort_t*       A[3][2];     // [pe,ve,dec][ping,pong] 1024 x KP_ bf16
    const ushort_t* W[3];        // packed 4096 x KP_ bf16
    const float*    bias[3];
    float*          c_pe; float* c_ve;
    const ushort_t* pose_bf; const ushort_t* vel_bf;
    const ushort_t* fcWb; const float* fcb;
    float*          accp; float* out;
};

// ---------------------------------------------------------------------------
// Persistent cooperative kernel, 256 blocks x 512 threads (1 block/CU).
// Encoder: blk -> p=blk&1, q=(blk>>1)&3, g5=blk>>3  => XCD blk%8 hosts one
// (p,q): all per-step h flows stay on one L2. Decoder: oct=blk&7 likewise.
// W + c in registers: immune to the per-sync cache invalidations that made
// round-5's persistent kernel refetch 1.75 GB.
// ---------------------------------------------------------------------------
__global__ __launch_bounds__(512, 2)
void main_kernel(MainArgs ma)
{
    cg::grid_group grid = cg::this_grid();
    __shared__ __align__(16) char lds[LDS_TOT];
    const int tid = threadIdx.x;
    const int w = tid >> 6, l = tid & 63;
    const int blk = blockIdx.x;

    // encoder geometry
    const int p  = blk & 1;
    const int q  = (blk >> 1) & 3;
    const int g5 = blk >> 3;
    const int j0w = (g5 << 5) + (w << 2);

    bf16x8 bw[NKT];
    load_w(bw, ma.W[p], j0w, l);
    const int jl = j0w + (l & 3);
    float bsi = ma.bias[p][jl];
    float bsf = ma.bias[p][1024 + jl];
    float bsg = ma.bias[p][2048 + jl];
    float bso = ma.bias[p][3072 + jl];

    float crA[8], crB[8];
    #pragma unroll
    for (int m = 0; m < 8; ++m) { crA[m] = 0.f; crB[m] = 0.f; }

    float* cglob = (p == 0) ? ma.c_pe : ma.c_ve;
    const int tlast = (p == 0) ? 49 : 48;

    // ---------------- encoders: 50 steps ----------------
    for (int t = 0; t < 50; ++t) {
        if (p == 0 || t < 49) {
            const ushort_t* Ain = ma.A[p][t & 1];
            ushort_t* Aout = ma.A[p][(t + 1) & 1];
            if (g5 == 0) {   // x_{t+1} copy for this (p,q)'s 256 rows
                const ushort_t* xn = nullptr; int xstr = 0;
                if (p == 0 && t < 49) { xn = ma.pose_bf + (size_t)(t + 1) * 75; xstr = 3750; }
                if (p == 1 && t < 48) { xn = ma.vel_bf  + (size_t)(t + 1) * 75; xstr = 3675; }
                if (xn) {
                    for (int i = tid; i < 256 * 75; i += 512) {
                        const int r = i / 75, f = i - r * 75;
                        Aout[(size_t)(q * 256 + r) * KP_ + 1024 + f] =
                            xn[(size_t)(q * 256 + r) * xstr + f];
                    }
                }
            }
            const int wc = (t == tlast);
            run_pass(lds, Ain, Aout, bw, crA, bsi, bsf, bsg, bso,
                     q * 256,       j0w, tid, w, l, wc, cglob);
            run_pass(lds, Ain, Aout, bw, crB, bsi, bsf, bsg, bso,
                     q * 256 + 128, j0w, tid, w, l, wc, cglob);
        }
        grid.sync();
    }

    // ---------------- combine (cross-XCD boundary; fenced) ----------------
    __threadfence();
    grid.sync();
    {
        const ushort_t* hpe = ma.A[0][0];
        const ushort_t* hve = ma.A[1][1];
        ushort_t* Ad = ma.A[2][0];
        for (int k = tid; k < 4096; k += 512) {
            const int idx = (blk << 12) + k;
            const size_t o = (size_t)(idx >> 10) * KP_ + (idx & 1023);
            Ad[o] = f2bf(bf2f(hpe[o]) + bf2f(hve[o]));
        }
    }
    __threadfence();
    grid.sync();

    // ---------------- decoder init: reload W, fold c_pe+c_ve ----------------
    const int oct = blk & 7;
    const int dj0w = ((blk >> 3) << 5) + (w << 2);
    load_w(bw, ma.W[2], dj0w, l);
    {
        const int jd = dj0w + (l & 3);
        bsi = ma.bias[2][jd];
        bsf = ma.bias[2][1024 + jd];
        bsg = ma.bias[2][2048 + jd];
        bso = ma.bias[2][3072 + jd];
        const int row2 = l >> 2, jj = l & 3;
        #pragma unroll
        for (int m = 0; m < 8; ++m) {
            const size_t o = ((size_t)(oct * 128 + m * 16 + row2) << 10) + dj0w + jj;
            crA[m] = ma.c_pe[o] + ma.c_ve[o];
        }
    }

    // ---------------- decoder: 49 x (step ; fc) ----------------
    for (int d = 0; d < 49; ++d) {
        const ushort_t* Ain = ma.A[2][d & 1];
        ushort_t* Aout = ma.A[2][(d + 1) & 1];
        run_pass(lds, Ain, Aout, bw, crA, bsi, bsf, bsg, bso,
                 oct * 128, dj0w, tid, w, l, 0, nullptr);
        grid.sync();
        fc_phase(lds, Aout, ma.fcWb, ma.fcb, ma.accp, ma.out, d, tid, blk);
        grid.sync();
    }
}

// ---------------------------------------------------------------------------
// Pack / prep (proven, unchanged).
// ---------------------------------------------------------------------------
__global__ __launch_bounds__(256)
void pack_kernel(const float* __restrict__ peWih, const float* __restrict__ peWhh,
                 const float* __restrict__ veWih, const float* __restrict__ veWhh,
                 const float* __restrict__ deWih, const float* __restrict__ deWhh,
                 const float* __restrict__ pe_bih, const float* __restrict__ pe_bhh,
                 const float* __restrict__ ve_bih, const float* __restrict__ ve_bhh,
                 const float* __restrict__ de_bih, const float* __restrict__ de_bhh,
                 const float* __restrict__ fcW,
                 ushort_t* __restrict__ Wp, float* __restrict__ biasp,
                 ushort_t* __restrict__ fcWb)
{
    const size_t PER = 4096UL * KP_;
    const size_t NW  = 3UL * PER;
    const size_t NB  = 3UL * 4096;
    const size_t NF  = 75UL * 1024;
    for (size_t idx = (size_t)blockIdx.x * blockDim.x + threadIdx.x;
         idx < NW + NB + NF; idx += (size_t)gridDim.x * blockDim.x) {
        if (idx < NW) {
            const int pp  = (int)(idx / PER);
            const size_t rem = idx % PER;
            const int row = (int)(rem / KP_);
            const int k   = (int)(rem % KP_);
            const float* Whh = (pp == 0) ? peWhh : (pp == 1) ? veWhh : deWhh;
            const float* Wih = (pp == 0) ? peWih : (pp == 1) ? veWih : deWih;
            float v = 0.f;
            if (k < 1024)      v = Whh[(size_t)row * 1024 + k];
            else if (k < 1099) v = Wih[(size_t)row * 75 + (k - 1024)];
            Wp[idx] = f2bf(v);
        } else if (idx < NW + NB) {
            const size_t i = idx - NW;
            const int pp = (int)(i / 4096);
            const int r = (int)(i % 4096);
            const float* bih = (pp == 0) ? pe_bih : (pp == 1) ? ve_bih : de_bih;
            const float* bhh = (pp == 0) ? pe_bhh : (pp == 1) ? ve_bhh : de_bhh;
            biasp[i] = bih[r] + bhh[r];
        } else {
            const size_t i = idx - NW - NB;
            fcWb[i] = f2bf(fcW[i]);
        }
    }
}

__global__ __launch_bounds__(256)
void prep_kernel(const float* __restrict__ pose, const float* __restrict__ fut,
                 const int* __restrict__ noise,
                 ushort_t* __restrict__ pose_bf, ushort_t* __restrict__ vel_bf,
                 ushort_t* __restrict__ A_pe0, ushort_t* __restrict__ A_ve0,
                 ushort_t* __restrict__ A_dec0,
                 float* __restrict__ accp, float* __restrict__ out)
{
    const size_t N0 = 1024UL * 50 * 75;
    const size_t N1 = 1024UL * 49 * 75;
    const size_t N2 = 1920000UL;
    const size_t N3 = 76800UL;
    for (size_t idx = (size_t)blockIdx.x * blockDim.x + threadIdx.x;
         idx < N0 + N1 + N2 + N3; idx += (size_t)gridDim.x * blockDim.x) {
        if (idx < N0) {
            pose_bf[idx] = f2bf(pose[idx]);
        } else if (idx < N0 + N1) {
            const size_t i = idx - N0;
            const int f = (int)(i % 75);
            const size_t rem = i / 75;
            const int t = (int)(rem % 49);
            const size_t b = rem / 49;
            float v = pose[(b * 50 + t + 1) * 75 + f] - pose[(b * 50 + t) * 75 + f];
            if (noise[(b * 50 + t + 1) * 25 + f / 3] == 1) v = 0.f;
            const ushort_t vb = f2bf(v);
            vel_bf[i] = vb;
            if (t == 0)  A_ve0[b * KP_ + 1024 + f]  = vb;
            if (t == 48) A_dec0[b * KP_ + 1024 + f] = vb;
        } else if (idx < N0 + N1 + N2) {
            const size_t i = idx - N0 - N1;
            out[i] = fut[i];
        } else {
            const size_t i = idx - N0 - N1 - N2;
            const size_t b = i / 75;
            const int f = (int)(i % 75);
            const float p0 = pose[b * 50 * 75 + f];
            A_pe0[b * KP_ + 1024 + f] = f2bf(p0);
            accp[i] = p0;
            out[OFF_CP + b * 50 * 75 + f] = p0;
        }
    }
}

// ---------------------------------------------------------------------------
// Multi-dispatch fallback (round-3 structure, proven 4.06 ms) — only used if
// the cooperative launch is rejected.
// ---------------------------------------------------------------------------
__device__ __forceinline__ void fb_body(
    char* lds,
    const ushort_t* __restrict__ Ain, ushort_t* __restrict__ Aout,
    const ushort_t* __restrict__ Wt,  const float* __restrict__ bias,
    float* __restrict__ cst,
    const ushort_t* xnext, int xstride,
    int ct, int rt, int tid)
{
    const int w = tid >> 6, l = tid & 63;
    const int j0 = ct * 64, row0 = rt * 64;
    if (ct == 0 && xnext) {
        for (int idx = tid; idx < 64 * 96; idx += 256) {
            const int r = idx / 96, xi = idx - r * 96;
            ushort_t v = (xi < FEAT_) ? xnext[(size_t)(row0 + r) * xstride + xi] : (ushort_t)0;
            Aout[(size_t)(row0 + r) * KP_ + 1024 + xi] = v;
        }
    }
    asm volatile("s_waitcnt vmcnt(0)" ::: "memory");
    const int lc4 = l & 3, lr4 = l >> 2;
    const int csrc = lc4 ^ (lr4 & 3);
    const ushort_t* agsrc = Ain + (size_t)(row0 + w * 16 + lr4) * KP_ + csrc * 8;
    char* aldst = lds + (w * 16) * 64;
    const ushort_t* bgsrc[4]; char* bldst[4];
    #pragma unroll
    for (int i = 0; i < 4; ++i) {
        bgsrc[i] = Wt + (size_t)(w * 1024 + j0 + i * 16 + lr4) * KP_ + csrc * 8;
        bldst[i] = lds + 4096 + (w * 64 + i * 16) * 64;
    }
    const int chsw = (((l >> 4) ^ (l & 3)) << 4);
    int aoff[4], boff[4];
    #pragma unroll
    for (int m = 0; m < 4; ++m) aoff[m] = (m * 16 + (l & 15)) * 64 + chsw;
    #pragma unroll
    for (int g = 0; g < 4; ++g) boff[g] = 4096 + (g * 64 + w * 16 + (l & 15)) * 64 + chsw;
    f32x4 acc[4][4];
    #pragma unroll
    for (int m = 0; m < 4; ++m)
        #pragma unroll
        for (int g = 0; g < 4; ++g) acc[m][g] = (f32x4){0.f,0.f,0.f,0.f};
    gload16(agsrc, aldst);
    #pragma unroll
    for (int i = 0; i < 4; ++i) gload16(bgsrc[i], bldst[i]);
    int bi = 0;
    for (int kt = 0; kt < NKT; ++kt) {
        if (kt + 1 < NKT) {
            const size_t k0 = (size_t)(kt + 1) * 32;
            const int nb = (bi ^ 1) * 20480;
            gload16(agsrc + k0, aldst + nb);
            #pragma unroll
            for (int i = 0; i < 4; ++i) gload16(bgsrc[i] + k0, bldst[i] + nb);
            asm volatile("s_waitcnt vmcnt(5)" ::: "memory");
        } else {
            asm volatile("s_waitcnt vmcnt(0)" ::: "memory");
        }
        __builtin_amdgcn_s_barrier();
        asm volatile("" ::: "memory");
        const char* bp = lds + bi * 20480;
        bf16x8 a[4], b[4];
        #pragma unroll
        for (int m = 0; m < 4; ++m) a[m] = *(const bf16x8*)(bp + aoff[m]);
        #pragma unroll
        for (int g = 0; g < 4; ++g) b[g] = *(const bf16x8*)(bp + boff[g]);
        #pragma unroll
        for (int m = 0; m < 4; ++m)
            #pragma unroll
            for (int g = 0; g < 4; ++g)
                acc[m][g] = __builtin_amdgcn_mfma_f32_16x16x32_bf16(a[m], b[g], acc[m][g], 0, 0, 0);
        asm volatile("" ::: "memory");
        __builtin_amdgcn_s_barrier();
        bi ^= 1;
    }
    const int jw = j0 + w * 16 + (l & 15);
    const float b_i = bias[jw], b_f = bias[1024 + jw], b_g = bias[2048 + jw], b_o = bias[3072 + jw];
    #pragma unroll
    for (int m = 0; m < 4; ++m)
        #pragma unroll
        for (int r = 0; r < 4; ++r) {
            const int grow = row0 + m * 16 + ((l >> 4) << 2) + r;
            const float cn = sigm(acc[m][1][r] + b_f) * cst[(size_t)grow * H_ + jw]
                           + sigm(acc[m][0][r] + b_i) * tanhf(acc[m][2][r] + b_g);
            cst[(size_t)grow * H_ + jw] = cn;
            Aout[(size_t)grow * KP_ + jw] = f2bf(sigm(acc[m][3][r] + b_o) * tanhf(cn));
        }
}

struct StepArgs {
    const ushort_t* Ain[2]; ushort_t* Aout[2];
    const ushort_t* W[2]; const float* bias[2]; float* c[2];
    const ushort_t* xnext[2]; int xstride[2];
};

__global__ __launch_bounds__(256)
void fb_step_kernel(StepArgs sa)
{
    __shared__ __align__(16) char lds[2 * 20480];
    const int flat = blockIdx.x, xcd = flat & 7, slot = flat >> 3;
    int pp, ct;
    if (gridDim.x == 512) { const int cgx = (xcd << 2) + (slot >> 4); pp = cgx >> 4; ct = cgx & 15; }
    else                  { const int cgx = (xcd << 1) + (slot >> 4); pp = 0;        ct = cgx; }
    fb_body(lds, sa.Ain[pp], sa.Aout[pp], sa.W[pp], sa.bias[pp], sa.c[pp],
            sa.xnext[pp], sa.xstride[pp], ct, slot & 15, threadIdx.x);
}

__global__ __launch_bounds__(256)
void fb_combine_kernel(const ushort_t* hpe, const ushort_t* hve,
                       const float* cpe, const float* cve,
                       ushort_t* Adec0, float* cde)
{
    const int idx = blockIdx.x * 256 + threadIdx.x;
    if (idx >= B_ * H_) return;
    const size_t o = (size_t)(idx >> 10) * KP_ + (idx & 1023);
    Adec0[o] = f2bf(bf2f(hpe[o]) + bf2f(hve[o]));
    cde[idx] = cpe[idx] + cve[idx];
}

__global__ __launch_bounds__(128)
void fb_fc_kernel(ushort_t* __restrict__ Adec,
                  const ushort_t* __restrict__ fcWb, const float* __restrict__ fcb,
                  float* __restrict__ accp, float* __restrict__ out, int t)
{
    __shared__ float hsf[1024];
    const int b = blockIdx.x;
    {
        const int k = threadIdx.x * 8;
        const bf16x8 v = *(const bf16x8*)(Adec + (size_t)b * KP_ + k);
        #pragma unroll
        for (int u = 0; u < 8; ++u) hsf[k + u] = bf2f((ushort_t)v[u]);
    }
    __syncthreads();
    const int f = threadIdx.x;
    if (f < FEAT_) {
        const ushort_t* wr = fcWb + (size_t)f * 1024;
        float s0 = fcb[f], s1 = 0.f, s2 = 0.f, s3 = 0.f;
        for (int k = 0; k < 1024; k += 32) {
            const bf16x8 w0 = *(const bf16x8*)(wr + k);
            const bf16x8 w1 = *(const bf16x8*)(wr + k + 8);
            const bf16x8 w2 = *(const bf16x8*)(wr + k + 16);
            const bf16x8 w3 = *(const bf16x8*)(wr + k + 24);
            #pragma unroll
            for (int u = 0; u < 8; ++u) {
                s0 = fmaf(hsf[k + u],      bf2f((ushort_t)w0[u]), s0);
                s1 = fmaf(hsf[k + 8 + u],  bf2f((ushort_t)w1[u]), s1);
                s2 = fmaf(hsf[k + 16 + u], bf2f((ushort_t)w2[u]), s2);
                s3 = fmaf(hsf[k + 24 + u], bf2f((ushort_t)w3[u]), s3);
            }
        }
        float s = (s0 + s1) + (s2 + s3);
        s = fminf(fmaxf(s, -1.f), 1.f);
        const float pnew = accp[b * FEAT_ + f] + s;
        accp[b * FEAT_ + f] = pnew;
        out[OFF_CV + ((size_t)b * 49 + t) * FEAT_ + f]     = s;
        out[OFF_CP + ((size_t)b * 50 + t + 1) * FEAT_ + f] = pnew;
        Adec[(size_t)b * KP_ + 1024 + f] = f2bf(s);
    }
}

extern "C" void kernel_launch(void* const* d_in, const int* in_sizes, int n_in,
                              void* d_out, int out_size, void* d_ws, size_t ws_size,
                              hipStream_t stream) {
    const float* pose   = (const float*)d_in[0];
    const float* fut    = (const float*)d_in[1];
    const int*   noise  = (const int*)  d_in[2];
    const float* peWih  = (const float*)d_in[3];
    const float* peWhh  = (const float*)d_in[4];
    const float* pe_bih = (const float*)d_in[5];
    const float* pe_bhh = (const float*)d_in[6];
    const float* veWih  = (const float*)d_in[7];
    const float* veWhh  = (const float*)d_in[8];
    const float* ve_bih = (const float*)d_in[9];
    const float* ve_bhh = (const float*)d_in[10];
    const float* deWih  = (const float*)d_in[11];
    const float* deWhh  = (const float*)d_in[12];
    const float* de_bih = (const float*)d_in[13];
    const float* de_bhh = (const float*)d_in[14];
    const float* fcW    = (const float*)d_in[15];
    const float* fcb    = (const float*)d_in[16];
    float* out = (float*)d_out;

    char* base = (char*)d_ws;
    ushort_t* Ape[2]  = {(ushort_t*)(base + 0UL * 2293760), (ushort_t*)(base + 1UL * 2293760)};
    ushort_t* Ave[2]  = {(ushort_t*)(base + 2UL * 2293760), (ushort_t*)(base + 3UL * 2293760)};
    ushort_t* Adec[2] = {(ushort_t*)(base + 4UL * 2293760), (ushort_t*)(base + 5UL * 2293760)};
    float* c_pe = (float*)(base + 13762560);
    float* c_ve = c_pe + 1048576;
    float* c_de = c_ve + 1048576;
    ushort_t* Wp    = (ushort_t*)(base + 26345472);   // 3 x 4096 x 1120
    float*    biasp = (float*)   (base + 53870592);   // 3 x 4096
    ushort_t* fcWb  = (ushort_t*)(base + 53919744);   // 75 x 1024
    ushort_t* pose_bf = (ushort_t*)(base + 54073344); // 1024x50x75
    ushort_t* vel_bf  = (ushort_t*)(base + 61753344); // 1024x49x75
    float*    accp    = (float*)   (base + 69279744); // 1024x75

    hipMemsetAsync(base, 0, 13762560, stream);   // 6 A buffers

    pack_kernel<<<2048, 256, 0, stream>>>(peWih, peWhh, veWih, veWhh, deWih, deWhh,
                                          pe_bih, pe_bhh, ve_bih, ve_bhh, de_bih, de_bhh,
                                          fcW, Wp, biasp, fcWb);
    prep_kernel<<<2048, 256, 0, stream>>>(pose, fut, noise, pose_bf, vel_bf,
                                          Ape[0], Ave[0], Adec[0], accp, out);

    MainArgs ma;
    ma.A[0][0] = Ape[0];  ma.A[0][1] = Ape[1];
    ma.A[1][0] = Ave[0];  ma.A[1][1] = Ave[1];
    ma.A[2][0] = Adec[0]; ma.A[2][1] = Adec[1];
    ma.W[0] = Wp; ma.W[1] = Wp + 4587520; ma.W[2] = Wp + 9175040;
    ma.bias[0] = biasp; ma.bias[1] = biasp + 4096; ma.bias[2] = biasp + 8192;
    ma.c_pe = c_pe; ma.c_ve = c_ve;
    ma.pose_bf = pose_bf; ma.vel_bf = vel_bf;
    ma.fcWb = fcWb; ma.fcb = fcb; ma.accp = accp; ma.out = out;

    void* kargs[] = {(void*)&ma};
    hipError_t e = hipLaunchCooperativeKernel((const void*)main_kernel,
                                              dim3(256), dim3(512), kargs, 0, stream);
    if (e != hipSuccess) {
        (void)hipGetLastError();
        // ---- proven multi-dispatch fallback (round-3 path, ~4.06 ms) ----
        for (int t = 0; t < 49; ++t) {
            StepArgs sa;
            sa.Ain[0] = Ape[t & 1];  sa.Aout[0] = Ape[(t + 1) & 1];
            sa.W[0] = ma.W[0]; sa.bias[0] = biasp; sa.c[0] = c_pe;
            sa.xnext[0] = pose_bf + (size_t)(t + 1) * 75; sa.xstride[0] = 3750;
            sa.Ain[1] = Ave[t & 1];  sa.Aout[1] = Ave[(t + 1) & 1];
            sa.W[1] = ma.W[1]; sa.bias[1] = biasp + 4096; sa.c[1] = c_ve;
            sa.xnext[1] = (t < 48) ? (vel_bf + (size_t)(t + 1) * 75) : nullptr;
            sa.xstride[1] = 3675;
            fb_step_kernel<<<512, 256, 0, stream>>>(sa);
        }
        {
            StepArgs sa;
            sa.Ain[0] = Ape[1]; sa.Aout[0] = Ape[0];
            sa.W[0] = ma.W[0]; sa.bias[0] = biasp; sa.c[0] = c_pe;
            sa.xnext[0] = nullptr; sa.xstride[0] = 3750;
            sa.Ain[1] = sa.Ain[0]; sa.Aout[1] = sa.Aout[0];
            sa.W[1] = sa.W[0]; sa.bias[1] = sa.bias[0]; sa.c[1] = sa.c[0];
            sa.xnext[1] = nullptr; sa.xstride[1] = 3750;
            fb_step_kernel<<<256, 256, 0, stream>>>(sa);
        }
        fb_combine_kernel<<<4096, 256, 0, stream>>>(Ape[0], Ave[1], c_pe, c_ve, Adec[0], c_de);
        for (int d = 0; d < 49; ++d) {
            StepArgs sa;
            sa.Ain[0] = Adec[d & 1]; sa.Aout[0] = Adec[(d + 1) & 1];
            sa.W[0] = ma.W[2]; sa.bias[0] = biasp + 8192; sa.c[0] = c_de;
            sa.xnext[0] = nullptr; sa.xstride[0] = 0;
            sa.Ain[1] = sa.Ain[0]; sa.Aout[1] = sa.Aout[0];
            sa.W[1] = sa.W[0]; sa.bias[1] = sa.bias[0]; sa.c[1] = sa.c[0];
            sa.xnext[1] = nullptr; sa.xstride[1] = 0;
            fb_step_kernel<<<256, 256, 0, stream>>>(sa);
            fb_fc_kernel<<<B_, 128, 0, stream>>>(Adec[(d + 1) & 1], fcWb, fcb, accp, out, d);
        }
    }
}

// Round 8
// 7806.509 us; speedup vs baseline: 1.0020x; 1.0020x over previous
//
#include <hip/hip_runtime.h>
#include <hip/hip_cooperative_groups.h>

namespace cg = cooperative_groups;

typedef unsigned short ushort_t;
typedef __attribute__((ext_vector_type(8))) short bf16x8;
typedef __attribute__((ext_vector_type(4))) float f32x4;

#define B_    1024
#define H_    1024
#define FEAT_ 75
#define KP_   1120          // packed K: 1024 h + 75 x + 21 zero pad
#define NKT   35            // K-steps of 32
#define OFF_CP 1920000UL    // 1024*25*75
#define OFF_CV 5760000UL    // OFF_CP + 1024*50*75

// LDS map (bytes) for main_kernel
#define LDS_SCR 24576       // after 3x8192 stage buffers; 8 waves x 1088B
#define LDS_FC  33280       // fc h-rows: 4x1024 f32
#define LDS_TOT 49664

__device__ __forceinline__ float bf2f(ushort_t u) {
    unsigned x = ((unsigned)u) << 16;
    float f; __builtin_memcpy(&f, &x, 4); return f;
}
__device__ __forceinline__ ushort_t f2bf(float f) {
    unsigned x; __builtin_memcpy(&x, &f, 4);
    x += 0x7fffu + ((x >> 16) & 1u);          // RNE
    return (ushort_t)(x >> 16);
}
__device__ __forceinline__ float sigm(float x) { return 1.f / (1.f + __expf(-x)); }

__device__ __forceinline__ void gload16(const void* g, void* l) {
    __builtin_amdgcn_global_load_lds(
        (const __attribute__((address_space(1))) void*)g,
        (__attribute__((address_space(3))) void*)l, 16, 0, 0);
}

// ---------------------------------------------------------------------------
// W-fragments into registers: wave owns 16 gate-cols (4 hidden j x 4 gates),
// 35 K-fragments of bf16x8 = 140 VGPRs, held across all timesteps.
// Fragment: lane l -> gate-col c=l&15 (g=c>>2, jj=c&3), k = kt*32+(l>>4)*8.
// ---------------------------------------------------------------------------
__device__ __forceinline__ void load_w(bf16x8 (&bw)[NKT],
                                       const ushort_t* __restrict__ Wt,
                                       int j0w, int l)
{
    const int c16 = l & 15;
    const size_t row = (size_t)((c16 >> 2) << 10) + (c16 & 3) + j0w;
    const ushort_t* p = Wt + row * KP_ + ((l >> 4) << 3);
    #pragma unroll
    for (int kt = 0; kt < NKT; ++kt)
        bw[kt] = *(const bf16x8*)(p + kt * 32);
}

// ---------------------------------------------------------------------------
// One M=128 GEMM pass + fused LSTM cell. B (weights) from registers; A staged
// via global_load_lds, triple-buffered with counted vmcnt.
// Epilogue: per-wave LDS scratch transposes the 16x16 gate tile so each lane
// gets all 4 gates of one (row, j); c kept in caller's register array.
// (Correctness-proven in round 7, absmax 0.031.)
// ---------------------------------------------------------------------------
__device__ __forceinline__ void run_pass(
    char* lds, const ushort_t* __restrict__ Ain, ushort_t* __restrict__ Aout,
    const bf16x8 (&bw)[NKT], float (&cr)[8],
    float bsi, float bsf, float bsg, float bso,
    int R0, int j0w, int tid, int w, int l,
    int write_c, float* __restrict__ cglob)
{
    const int srow = tid >> 2;
    const ushort_t* asrc = Ain + (size_t)(R0 + srow) * KP_
                         + (((tid & 3) ^ (srow & 3)) << 3);   // inv-swizzled src
    char* adst = lds + (w << 10);                              // wave-uniform
    const int abase = ((l & 15) << 6) + ((((l >> 4) ^ (l & 3))) << 4);
    float* sc = (float*)(lds + LDS_SCR) + w * 272;             // 16x17 f32

    f32x4 acc[8];
    #pragma unroll
    for (int m = 0; m < 8; ++m) acc[m] = (f32x4){0.f, 0.f, 0.f, 0.f};

    asm volatile("s_waitcnt vmcnt(0)" ::: "memory");   // pin vm counter base
    gload16(asrc,      adst);
    gload16(asrc + 32, adst + 8192);

    #pragma unroll
    for (int kt = 0; kt < NKT; ++kt) {
        if (kt + 2 < NKT) {
            gload16(asrc + (kt + 2) * 32, adst + ((kt + 2) % 3) * 8192);
            asm volatile("s_waitcnt vmcnt(2)" ::: "memory");
        } else if (kt + 1 < NKT) {
            asm volatile("s_waitcnt vmcnt(1)" ::: "memory");
        } else {
            asm volatile("s_waitcnt vmcnt(0)" ::: "memory");
        }
        __builtin_amdgcn_s_barrier();
        asm volatile("" ::: "memory");
        const char* bp = lds + (kt % 3) * 8192;
        __builtin_amdgcn_s_setprio(1);
        #pragma unroll
        for (int m = 0; m < 8; ++m) {
            const bf16x8 a = *(const bf16x8*)(bp + (m << 10) + abase);
            acc[m] = __builtin_amdgcn_mfma_f32_16x16x32_bf16(a, bw[kt], acc[m], 0, 0, 0);
        }
        __builtin_amdgcn_s_setprio(0);
        asm volatile("" ::: "memory");
        __builtin_amdgcn_s_barrier();
    }

    const int row2 = l >> 2, jj = l & 3;
    const int jcol = j0w + jj;
    #pragma unroll
    for (int m = 0; m < 8; ++m) {
        #pragma unroll
        for (int r = 0; r < 4; ++r)
            sc[((l >> 4) * 4 + r) * 17 + (l & 15)] = acc[m][r];
        const float gi = sc[row2 * 17 + jj];
        const float gf = sc[row2 * 17 + 4 + jj];
        const float gg = sc[row2 * 17 + 8 + jj];
        const float go = sc[row2 * 17 + 12 + jj];
        const float cn = sigm(gf + bsf) * cr[m] + sigm(gi + bsi) * tanhf(gg + bsg);
        cr[m] = cn;
        const int grow = R0 + (m << 4) + row2;
        Aout[(size_t)grow * KP_ + jcol] = f2bf(sigm(go + bso) * tanhf(cn));
        if (write_c) cglob[((size_t)grow << 10) + jcol] = cn;
    }
}

// ---------------------------------------------------------------------------
// fc phase (decoder): block handles 4 batch rows aligned with its XCD's step
// writers. Fuses clip, comp_vel/comp_pose writes, cumsum, x-feedback.
// ---------------------------------------------------------------------------
__device__ __forceinline__ void fc_phase(
    char* lds, ushort_t* __restrict__ Ah,
    const ushort_t* __restrict__ fcWb, const float* __restrict__ fcb,
    float* __restrict__ accp, float* __restrict__ out,
    int d, int tid, int blk)
{
    float* hs = (float*)(lds + LDS_FC);
    const int r0 = (blk & 7) * 128 + (blk >> 3) * 4;
    {
        const int r = tid >> 7, k8 = (tid & 127) << 3;
        const bf16x8 v = *(const bf16x8*)(Ah + (size_t)(r0 + r) * KP_ + k8);
        #pragma unroll
        for (int u = 0; u < 8; ++u) hs[(r << 10) + k8 + u] = bf2f((ushort_t)v[u]);
    }
    __syncthreads();
    const int r = tid >> 7, f = tid & 127;
    if (f < FEAT_) {
        const ushort_t* wr = fcWb + (size_t)f * 1024;
        const float* hr = hs + (r << 10);
        float s0 = fcb[f], s1 = 0.f, s2 = 0.f, s3 = 0.f;
        for (int k = 0; k < 1024; k += 32) {
            const bf16x8 w0 = *(const bf16x8*)(wr + k);
            const bf16x8 w1 = *(const bf16x8*)(wr + k + 8);
            const bf16x8 w2 = *(const bf16x8*)(wr + k + 16);
            const bf16x8 w3 = *(const bf16x8*)(wr + k + 24);
            #pragma unroll
            for (int u = 0; u < 8; ++u) {
                s0 = fmaf(hr[k + u],      bf2f((ushort_t)w0[u]), s0);
                s1 = fmaf(hr[k + 8 + u],  bf2f((ushort_t)w1[u]), s1);
                s2 = fmaf(hr[k + 16 + u], bf2f((ushort_t)w2[u]), s2);
                s3 = fmaf(hr[k + 24 + u], bf2f((ushort_t)w3[u]), s3);
            }
        }
        float s = (s0 + s1) + (s2 + s3);
        s = fminf(fmaxf(s, -1.f), 1.f);
        const int row = r0 + r;
        const float pnew = accp[row * FEAT_ + f] + s;
        accp[row * FEAT_ + f] = pnew;
        out[OFF_CV + ((size_t)row * 49 + d) * FEAT_ + f]     = s;
        out[OFF_CP + ((size_t)row * 50 + d + 1) * FEAT_ + f] = pnew;
        Ah[(size_t)row * KP_ + 1024 + f] = f2bf(s);
    }
    __syncthreads();
}

// ---------------------------------------------------------------------------
struct MainArgs {
    ushort_t*       A[3][2];     // [pe,ve,dec][ping,pong] 1024 x KP_ bf16
    const ushort_t* W[3];        // packed 4096 x KP_ bf16
    const float*    bias[3];
    float*          c_pe; float* c_ve;
    const ushort_t* pose_bf; const ushort_t* vel_bf;
    const ushort_t* fcWb; const float* fcb;
    float*          accp; float* out;
};

// ---------------------------------------------------------------------------
// Persistent cooperative kernel, 256 blocks x 512 threads (1 block/CU).
// launch_bounds(512, 1): VGPR cap 512/wave -> bw[35] (140 VGPRs) stays in
// registers. Round 7's (512,2) capped at 128 VGPR and spilled the whole
// weight array to scratch (VGPR_Count=128, WRITE_SIZE +200MB of spill).
// ---------------------------------------------------------------------------
__global__ __launch_bounds__(512, 1)
void main_kernel(MainArgs ma)
{
    cg::grid_group grid = cg::this_grid();
    __shared__ __align__(16) char lds[LDS_TOT];
    const int tid = threadIdx.x;
    const int w = tid >> 6, l = tid & 63;
    const int blk = blockIdx.x;

    // encoder geometry: XCD blk%8 hosts one (p,q) -> all h flows intra-L2
    const int p  = blk & 1;
    const int q  = (blk >> 1) & 3;
    const int g5 = blk >> 3;
    const int j0w = (g5 << 5) + (w << 2);

    bf16x8 bw[NKT];
    load_w(bw, ma.W[p], j0w, l);
    const int jl = j0w + (l & 3);
    float bsi = ma.bias[p][jl];
    float bsf = ma.bias[p][1024 + jl];
    float bsg = ma.bias[p][2048 + jl];
    float bso = ma.bias[p][3072 + jl];

    float crA[8], crB[8];
    #pragma unroll
    for (int m = 0; m < 8; ++m) { crA[m] = 0.f; crB[m] = 0.f; }

    float* cglob = (p == 0) ? ma.c_pe : ma.c_ve;
    const int tlast = (p == 0) ? 49 : 48;

    // ---------------- encoders: 50 steps ----------------
    for (int t = 0; t < 50; ++t) {
        if (p == 0 || t < 49) {
            const ushort_t* Ain = ma.A[p][t & 1];
            ushort_t* Aout = ma.A[p][(t + 1) & 1];
            if (g5 == 0) {   // x_{t+1} copy for this (p,q)'s 256 rows
                const ushort_t* xn = nullptr; int xstr = 0;
                if (p == 0 && t < 49) { xn = ma.pose_bf + (size_t)(t + 1) * 75; xstr = 3750; }
                if (p == 1 && t < 48) { xn = ma.vel_bf  + (size_t)(t + 1) * 75; xstr = 3675; }
                if (xn) {
                    for (int i = tid; i < 256 * 75; i += 512) {
                        const int r = i / 75, f = i - r * 75;
                        Aout[(size_t)(q * 256 + r) * KP_ + 1024 + f] =
                            xn[(size_t)(q * 256 + r) * xstr + f];
                    }
                }
            }
            const int wc = (t == tlast);
            run_pass(lds, Ain, Aout, bw, crA, bsi, bsf, bsg, bso,
                     q * 256,       j0w, tid, w, l, wc, cglob);
            run_pass(lds, Ain, Aout, bw, crB, bsi, bsf, bsg, bso,
                     q * 256 + 128, j0w, tid, w, l, wc, cglob);
        }
        grid.sync();
    }

    // ---------------- combine (cross-XCD boundary; fenced) ----------------
    __threadfence();
    grid.sync();
    {
        const ushort_t* hpe = ma.A[0][0];
        const ushort_t* hve = ma.A[1][1];
        ushort_t* Ad = ma.A[2][0];
        for (int k = tid; k < 4096; k += 512) {
            const int idx = (blk << 12) + k;
            const size_t o = (size_t)(idx >> 10) * KP_ + (idx & 1023);
            Ad[o] = f2bf(bf2f(hpe[o]) + bf2f(hve[o]));
        }
    }
    __threadfence();
    grid.sync();

    // ---------------- decoder init: reload W, fold c_pe+c_ve ----------------
    const int oct = blk & 7;
    const int dj0w = ((blk >> 3) << 5) + (w << 2);
    load_w(bw, ma.W[2], dj0w, l);
    {
        const int jd = dj0w + (l & 3);
        bsi = ma.bias[2][jd];
        bsf = ma.bias[2][1024 + jd];
        bsg = ma.bias[2][2048 + jd];
        bso = ma.bias[2][3072 + jd];
        const int row2 = l >> 2, jj = l & 3;
        #pragma unroll
        for (int m = 0; m < 8; ++m) {
            const size_t o = ((size_t)(oct * 128 + m * 16 + row2) << 10) + dj0w + jj;
            crA[m] = ma.c_pe[o] + ma.c_ve[o];
        }
    }

    // ---------------- decoder: 49 x (step ; fc) ----------------
    for (int d = 0; d < 49; ++d) {
        const ushort_t* Ain = ma.A[2][d & 1];
        ushort_t* Aout = ma.A[2][(d + 1) & 1];
        run_pass(lds, Ain, Aout, bw, crA, bsi, bsf, bsg, bso,
                 oct * 128, dj0w, tid, w, l, 0, nullptr);
        grid.sync();
        fc_phase(lds, Aout, ma.fcWb, ma.fcb, ma.accp, ma.out, d, tid, blk);
        grid.sync();
    }
}

// ---------------------------------------------------------------------------
// Pack / prep (proven, unchanged).
// ---------------------------------------------------------------------------
__global__ __launch_bounds__(256)
void pack_kernel(const float* __restrict__ peWih, const float* __restrict__ peWhh,
                 const float* __restrict__ veWih, const float* __restrict__ veWhh,
                 const float* __restrict__ deWih, const float* __restrict__ deWhh,
                 const float* __restrict__ pe_bih, const float* __restrict__ pe_bhh,
                 const float* __restrict__ ve_bih, const float* __restrict__ ve_bhh,
                 const float* __restrict__ de_bih, const float* __restrict__ de_bhh,
                 const float* __restrict__ fcW,
                 ushort_t* __restrict__ Wp, float* __restrict__ biasp,
                 ushort_t* __restrict__ fcWb)
{
    const size_t PER = 4096UL * KP_;
    const size_t NW  = 3UL * PER;
    const size_t NB  = 3UL * 4096;
    const size_t NF  = 75UL * 1024;
    for (size_t idx = (size_t)blockIdx.x * blockDim.x + threadIdx.x;
         idx < NW + NB + NF; idx += (size_t)gridDim.x * blockDim.x) {
        if (idx < NW) {
            const int pp  = (int)(idx / PER);
            const size_t rem = idx % PER;
            const int row = (int)(rem / KP_);
            const int k   = (int)(rem % KP_);
            const float* Whh = (pp == 0) ? peWhh : (pp == 1) ? veWhh : deWhh;
            const float* Wih = (pp == 0) ? peWih : (pp == 1) ? veWih : deWih;
            float v = 0.f;
            if (k < 1024)      v = Whh[(size_t)row * 1024 + k];
            else if (k < 1099) v = Wih[(size_t)row * 75 + (k - 1024)];
            Wp[idx] = f2bf(v);
        } else if (idx < NW + NB) {
            const size_t i = idx - NW;
            const int pp = (int)(i / 4096);
            const int r = (int)(i % 4096);
            const float* bih = (pp == 0) ? pe_bih : (pp == 1) ? ve_bih : de_bih;
            const float* bhh = (pp == 0) ? pe_bhh : (pp == 1) ? ve_bhh : de_bhh;
            biasp[i] = bih[r] + bhh[r];
        } else {
            const size_t i = idx - NW - NB;
            fcWb[i] = f2bf(fcW[i]);
        }
    }
}

__global__ __launch_bounds__(256)
void prep_kernel(const float* __restrict__ pose, const float* __restrict__ fut,
                 const int* __restrict__ noise,
                 ushort_t* __restrict__ pose_bf, ushort_t* __restrict__ vel_bf,
                 ushort_t* __restrict__ A_pe0, ushort_t* __restrict__ A_ve0,
                 ushort_t* __restrict__ A_dec0,
                 float* __restrict__ accp, float* __restrict__ out)
{
    const size_t N0 = 1024UL * 50 * 75;
    const size_t N1 = 1024UL * 49 * 75;
    const size_t N2 = 1920000UL;
    const size_t N3 = 76800UL;
    for (size_t idx = (size_t)blockIdx.x * blockDim.x + threadIdx.x;
         idx < N0 + N1 + N2 + N3; idx += (size_t)gridDim.x * blockDim.x) {
        if (idx < N0) {
            pose_bf[idx] = f2bf(pose[idx]);
        } else if (idx < N0 + N1) {
            const size_t i = idx - N0;
            const int f = (int)(i % 75);
            const size_t rem = i / 75;
            const int t = (int)(rem % 49);
            const size_t b = rem / 49;
            float v = pose[(b * 50 + t + 1) * 75 + f] - pose[(b * 50 + t) * 75 + f];
            if (noise[(b * 50 + t + 1) * 25 + f / 3] == 1) v = 0.f;
            const ushort_t vb = f2bf(v);
            vel_bf[i] = vb;
            if (t == 0)  A_ve0[b * KP_ + 1024 + f]  = vb;
            if (t == 48) A_dec0[b * KP_ + 1024 + f] = vb;
        } else if (idx < N0 + N1 + N2) {
            const size_t i = idx - N0 - N1;
            out[i] = fut[i];
        } else {
            const size_t i = idx - N0 - N1 - N2;
            const size_t b = i / 75;
            const int f = (int)(i % 75);
            const float p0 = pose[b * 50 * 75 + f];
            A_pe0[b * KP_ + 1024 + f] = f2bf(p0);
            accp[i] = p0;
            out[OFF_CP + b * 50 * 75 + f] = p0;
        }
    }
}

// ---------------------------------------------------------------------------
// Multi-dispatch fallback (round-3 structure, proven 4.06 ms) — only used if
// the cooperative launch is rejected.
// ---------------------------------------------------------------------------
__device__ __forceinline__ void fb_body(
    char* lds,
    const ushort_t* __restrict__ Ain, ushort_t* __restrict__ Aout,
    const ushort_t* __restrict__ Wt,  const float* __restrict__ bias,
    float* __restrict__ cst,
    const ushort_t* xnext, int xstride,
    int ct, int rt, int tid)
{
    const int w = tid >> 6, l = tid & 63;
    const int j0 = ct * 64, row0 = rt * 64;
    if (ct == 0 && xnext) {
        for (int idx = tid; idx < 64 * 96; idx += 256) {
            const int r = idx / 96, xi = idx - r * 96;
            ushort_t v = (xi < FEAT_) ? xnext[(size_t)(row0 + r) * xstride + xi] : (ushort_t)0;
            Aout[(size_t)(row0 + r) * KP_ + 1024 + xi] = v;
        }
    }
    asm volatile("s_waitcnt vmcnt(0)" ::: "memory");
    const int lc4 = l & 3, lr4 = l >> 2;
    const int csrc = lc4 ^ (lr4 & 3);
    const ushort_t* agsrc = Ain + (size_t)(row0 + w * 16 + lr4) * KP_ + csrc * 8;
    char* aldst = lds + (w * 16) * 64;
    const ushort_t* bgsrc[4]; char* bldst[4];
    #pragma unroll
    for (int i = 0; i < 4; ++i) {
        bgsrc[i] = Wt + (size_t)(w * 1024 + j0 + i * 16 + lr4) * KP_ + csrc * 8;
        bldst[i] = lds + 4096 + (w * 64 + i * 16) * 64;
    }
    const int chsw = (((l >> 4) ^ (l & 3)) << 4);
    int aoff[4], boff[4];
    #pragma unroll
    for (int m = 0; m < 4; ++m) aoff[m] = (m * 16 + (l & 15)) * 64 + chsw;
    #pragma unroll
    for (int g = 0; g < 4; ++g) boff[g] = 4096 + (g * 64 + w * 16 + (l & 15)) * 64 + chsw;
    f32x4 acc[4][4];
    #pragma unroll
    for (int m = 0; m < 4; ++m)
        #pragma unroll
        for (int g = 0; g < 4; ++g) acc[m][g] = (f32x4){0.f,0.f,0.f,0.f};
    gload16(agsrc, aldst);
    #pragma unroll
    for (int i = 0; i < 4; ++i) gload16(bgsrc[i], bldst[i]);
    int bi = 0;
    for (int kt = 0; kt < NKT; ++kt) {
        if (kt + 1 < NKT) {
            const size_t k0 = (size_t)(kt + 1) * 32;
            const int nb = (bi ^ 1) * 20480;
            gload16(agsrc + k0, aldst + nb);
            #pragma unroll
            for (int i = 0; i < 4; ++i) gload16(bgsrc[i] + k0, bldst[i] + nb);
            asm volatile("s_waitcnt vmcnt(5)" ::: "memory");
        } else {
            asm volatile("s_waitcnt vmcnt(0)" ::: "memory");
        }
        __builtin_amdgcn_s_barrier();
        asm volatile("" ::: "memory");
        const char* bp = lds + bi * 20480;
        bf16x8 a[4], b[4];
        #pragma unroll
        for (int m = 0; m < 4; ++m) a[m] = *(const bf16x8*)(bp + aoff[m]);
        #pragma unroll
        for (int g = 0; g < 4; ++g) b[g] = *(const bf16x8*)(bp + boff[g]);
        #pragma unroll
        for (int m = 0; m < 4; ++m)
            #pragma unroll
            for (int g = 0; g < 4; ++g)
                acc[m][g] = __builtin_amdgcn_mfma_f32_16x16x32_bf16(a[m], b[g], acc[m][g], 0, 0, 0);
        asm volatile("" ::: "memory");
        __builtin_amdgcn_s_barrier();
        bi ^= 1;
    }
    const int jw = j0 + w * 16 + (l & 15);
    const float b_i = bias[jw], b_f = bias[1024 + jw], b_g = bias[2048 + jw], b_o = bias[3072 + jw];
    #pragma unroll
    for (int m = 0; m < 4; ++m)
        #pragma unroll
        for (int r = 0; r < 4; ++r) {
            const int grow = row0 + m * 16 + ((l >> 4) << 2) + r;
            const float cn = sigm(acc[m][1][r] + b_f) * cst[(size_t)grow * H_ + jw]
                           + sigm(acc[m][0][r] + b_i) * tanhf(acc[m][2][r] + b_g);
            cst[(size_t)grow * H_ + jw] = cn;
            Aout[(size_t)grow * KP_ + jw] = f2bf(sigm(acc[m][3][r] + b_o) * tanhf(cn));
        }
}

struct StepArgs {
    const ushort_t* Ain[2]; ushort_t* Aout[2];
    const ushort_t* W[2]; const float* bias[2]; float* c[2];
    const ushort_t* xnext[2]; int xstride[2];
};

__global__ __launch_bounds__(256)
void fb_step_kernel(StepArgs sa)
{
    __shared__ __align__(16) char lds[2 * 20480];
    const int flat = blockIdx.x, xcd = flat & 7, slot = flat >> 3;
    int pp, ct;
    if (gridDim.x == 512) { const int cgx = (xcd << 2) + (slot >> 4); pp = cgx >> 4; ct = cgx & 15; }
    else                  { const int cgx = (xcd << 1) + (slot >> 4); pp = 0;        ct = cgx; }
    fb_body(lds, sa.Ain[pp], sa.Aout[pp], sa.W[pp], sa.bias[pp], sa.c[pp],
            sa.xnext[pp], sa.xstride[pp], ct, slot & 15, threadIdx.x);
}

__global__ __launch_bounds__(256)
void fb_combine_kernel(const ushort_t* hpe, const ushort_t* hve,
                       const float* cpe, const float* cve,
                       ushort_t* Adec0, float* cde)
{
    const int idx = blockIdx.x * 256 + threadIdx.x;
    if (idx >= B_ * H_) return;
    const size_t o = (size_t)(idx >> 10) * KP_ + (idx & 1023);
    Adec0[o] = f2bf(bf2f(hpe[o]) + bf2f(hve[o]));
    cde[idx] = cpe[idx] + cve[idx];
}

__global__ __launch_bounds__(128)
void fb_fc_kernel(ushort_t* __restrict__ Adec,
                  const ushort_t* __restrict__ fcWb, const float* __restrict__ fcb,
                  float* __restrict__ accp, float* __restrict__ out, int t)
{
    __shared__ float hsf[1024];
    const int b = blockIdx.x;
    {
        const int k = threadIdx.x * 8;
        const bf16x8 v = *(const bf16x8*)(Adec + (size_t)b * KP_ + k);
        #pragma unroll
        for (int u = 0; u < 8; ++u) hsf[k + u] = bf2f((ushort_t)v[u]);
    }
    __syncthreads();
    const int f = threadIdx.x;
    if (f < FEAT_) {
        const ushort_t* wr = fcWb + (size_t)f * 1024;
        float s0 = fcb[f], s1 = 0.f, s2 = 0.f, s3 = 0.f;
        for (int k = 0; k < 1024; k += 32) {
            const bf16x8 w0 = *(const bf16x8*)(wr + k);
            const bf16x8 w1 = *(const bf16x8*)(wr + k + 8);
            const bf16x8 w2 = *(const bf16x8*)(wr + k + 16);
            const bf16x8 w3 = *(const bf16x8*)(wr + k + 24);
            #pragma unroll
            for (int u = 0; u < 8; ++u) {
                s0 = fmaf(hsf[k + u],      bf2f((ushort_t)w0[u]), s0);
                s1 = fmaf(hsf[k + 8 + u],  bf2f((ushort_t)w1[u]), s1);
                s2 = fmaf(hsf[k + 16 + u], bf2f((ushort_t)w2[u]), s2);
                s3 = fmaf(hsf[k + 24 + u], bf2f((ushort_t)w3[u]), s3);
            }
        }
        float s = (s0 + s1) + (s2 + s3);
        s = fminf(fmaxf(s, -1.f), 1.f);
        const float pnew = accp[b * FEAT_ + f] + s;
        accp[b * FEAT_ + f] = pnew;
        out[OFF_CV + ((size_t)b * 49 + t) * FEAT_ + f]     = s;
        out[OFF_CP + ((size_t)b * 50 + t + 1) * FEAT_ + f] = pnew;
        Adec[(size_t)b * KP_ + 1024 + f] = f2bf(s);
    }
}

extern "C" void kernel_launch(void* const* d_in, const int* in_sizes, int n_in,
                              void* d_out, int out_size, void* d_ws, size_t ws_size,
                              hipStream_t stream) {
    const float* pose   = (const float*)d_in[0];
    const float* fut    = (const float*)d_in[1];
    const int*   noise  = (const int*)  d_in[2];
    const float* peWih  = (const float*)d_in[3];
    const float* peWhh  = (const float*)d_in[4];
    const float* pe_bih = (const float*)d_in[5];
    const float* pe_bhh = (const float*)d_in[6];
    const float* veWih  = (const float*)d_in[7];
    const float* veWhh  = (const float*)d_in[8];
    const float* ve_bih = (const float*)d_in[9];
    const float* ve_bhh = (const float*)d_in[10];
    const float* deWih  = (const float*)d_in[11];
    const float* deWhh  = (const float*)d_in[12];
    const float* de_bih = (const float*)d_in[13];
    const float* de_bhh = (const float*)d_in[14];
    const float* fcW    = (const float*)d_in[15];
    const float* fcb    = (const float*)d_in[16];
    float* out = (float*)d_out;

    char* base = (char*)d_ws;
    ushort_t* Ape[2]  = {(ushort_t*)(base + 0UL * 2293760), (ushort_t*)(base + 1UL * 2293760)};
    ushort_t* Ave[2]  = {(ushort_t*)(base + 2UL * 2293760), (ushort_t*)(base + 3UL * 2293760)};
    ushort_t* Adec[2] = {(ushort_t*)(base + 4UL * 2293760), (ushort_t*)(base + 5UL * 2293760)};
    float* c_pe = (float*)(base + 13762560);
    float* c_ve = c_pe + 1048576;
    float* c_de = c_ve + 1048576;
    ushort_t* Wp    = (ushort_t*)(base + 26345472);   // 3 x 4096 x 1120
    float*    biasp = (float*)   (base + 53870592);   // 3 x 4096
    ushort_t* fcWb  = (ushort_t*)(base + 53919744);   // 75 x 1024
    ushort_t* pose_bf = (ushort_t*)(base + 54073344); // 1024x50x75
    ushort_t* vel_bf  = (ushort_t*)(base + 61753344); // 1024x49x75
    float*    accp    = (float*)   (base + 69279744); // 1024x75

    hipMemsetAsync(base, 0, 13762560, stream);   // 6 A buffers

    pack_kernel<<<2048, 256, 0, stream>>>(peWih, peWhh, veWih, veWhh, deWih, deWhh,
                                          pe_bih, pe_bhh, ve_bih, ve_bhh, de_bih, de_bhh,
                                          fcW, Wp, biasp, fcWb);
    prep_kernel<<<2048, 256, 0, stream>>>(pose, fut, noise, pose_bf, vel_bf,
                                          Ape[0], Ave[0], Adec[0], accp, out);

    MainArgs ma;
    ma.A[0][0] = Ape[0];  ma.A[0][1] = Ape[1];
    ma.A[1][0] = Ave[0];  ma.A[1][1] = Ave[1];
    ma.A[2][0] = Adec[0]; ma.A[2][1] = Adec[1];
    ma.W[0] = Wp; ma.W[1] = Wp + 4587520; ma.W[2] = Wp + 9175040;
    ma.bias[0] = biasp; ma.bias[1] = biasp + 4096; ma.bias[2] = biasp + 8192;
    ma.c_pe = c_pe; ma.c_ve = c_ve;
    ma.pose_bf = pose_bf; ma.vel_bf = vel_bf;
    ma.fcWb = fcWb; ma.fcb = fcb; ma.accp = accp; ma.out = out;

    void* kargs[] = {(void*)&ma};
    hipError_t e = hipLaunchCooperativeKernel((const void*)main_kernel,
                                              dim3(256), dim3(512), kargs, 0, stream);
    if (e != hipSuccess) {
        (void)hipGetLastError();
        // ---- proven multi-dispatch fallback (round-3 path, ~4.06 ms) ----
        for (int t = 0; t < 49; ++t) {
            StepArgs sa;
            sa.Ain[0] = Ape[t & 1];  sa.Aout[0] = Ape[(t + 1) & 1];
            sa.W[0] = ma.W[0]; sa.bias[0] = biasp; sa.c[0] = c_pe;
            sa.xnext[0] = pose_bf + (size_t)(t + 1) * 75; sa.xstride[0] = 3750;
            sa.Ain[1] = Ave[t & 1];  sa.Aout[1] = Ave[(t + 1) & 1];
            sa.W[1] = ma.W[1]; sa.bias[1] = biasp + 4096; sa.c[1] = c_ve;
            sa.xnext[1] = (t < 48) ? (vel_bf + (size_t)(t + 1) * 75) : nullptr;
            sa.xstride[1] = 3675;
            fb_step_kernel<<<512, 256, 0, stream>>>(sa);
        }
        {
            StepArgs sa;
            sa.Ain[0] = Ape[1]; sa.Aout[0] = Ape[0];
            sa.W[0] = ma.W[0]; sa.bias[0] = biasp; sa.c[0] = c_pe;
            sa.xnext[0] = nullptr; sa.xstride[0] = 3750;
            sa.Ain[1] = sa.Ain[0]; sa.Aout[1] = sa.Aout[0];
            sa.W[1] = sa.W[0]; sa.bias[1] = sa.bias[0]; sa.c[1] = sa.c[0];
            sa.xnext[1] = nullptr; sa.xstride[1] = 3750;
            fb_step_kernel<<<256, 256, 0, stream>>>(sa);
        }
        fb_combine_kernel<<<4096, 256, 0, stream>>>(Ape[0], Ave[1], c_pe, c_ve, Adec[0], c_de);
        for (int d = 0; d < 49; ++d) {
            StepArgs sa;
            sa.Ain[0] = Adec[d & 1]; sa.Aout[0] = Adec[(d + 1) & 1];
            sa.W[0] = ma.W[2]; sa.bias[0] = biasp + 8192; sa.c[0] = c_de;
            sa.xnext[0] = nullptr; sa.xstride[0] = 0;
            sa.Ain[1] = sa.Ain[0]; sa.Aout[1] = sa.Aout[0];
            sa.W[1] = sa.W[0]; sa.bias[1] = sa.bias[0]; sa.c[1] = sa.c[0];
            sa.xnext[1] = nullptr; sa.xstride[1] = 0;
            fb_step_kernel<<<256, 256, 0, stream>>>(sa);
            fb_fc_kernel<<<B_, 128, 0, stream>>>(Adec[(d + 1) & 1], fcWb, fcb, accp, out, d);
        }
    }
}